// Round 4
// baseline (741.177 us; speedup 1.0000x reference)
//
#include <hip/hip_runtime.h>
#include <math.h>

#define SEQ 2048
#define DIM 2048
#define NH 16
#define DH 128
#define NKV 2304   /* DIM + 2*DH : fused q|k|v projection width */
#define KOFF 2048
#define VOFF 2176
#define QK_SCALE 0.08838834764831845f

#define NUNITS2 5120   /* chunked per-wave work units */
#define RECB 4224      /* partial record: 16x128 f16 o_n + 16 f32 m + 16 f32 l */
#define RECPH 288      /* records per head (g>=32 chunk count) */

typedef _Float16 f16;
typedef _Float16 f16x8 __attribute__((ext_vector_type(8)));
typedef _Float16 f16x4 __attribute__((ext_vector_type(4)));
typedef float f32x4 __attribute__((ext_vector_type(4)));

__device__ __forceinline__ void gload16(const f16* g, f16* l) {
    __builtin_amdgcn_global_load_lds(
        (const __attribute__((address_space(1))) void*)g,
        (__attribute__((address_space(3))) void*)l,
        16, 0, 0);
}
__device__ __forceinline__ void gload16f(const float* g, float* l) {
    __builtin_amdgcn_global_load_lds(
        (const __attribute__((address_space(1))) void*)g,
        (__attribute__((address_space(3))) void*)l,
        16, 0, 0);
}

// ---------------- RMSNorm + fp16 hi/lo split ----------------
__global__ __launch_bounds__(256) void rmsnorm_split_k(
    const float* __restrict__ x, const float* __restrict__ gamma,
    f16* __restrict__ oh, f16* __restrict__ ol)
{
    int row = blockIdx.x, tid = threadIdx.x;
    const float4* xr = (const float4*)(x + (size_t)row * DIM);
    float4 a0 = xr[tid], a1 = xr[tid + 256];
    float ss = a0.x*a0.x + a0.y*a0.y + a0.z*a0.z + a0.w*a0.w
             + a1.x*a1.x + a1.y*a1.y + a1.z*a1.z + a1.w*a1.w;
    #pragma unroll
    for (int off = 1; off < 64; off <<= 1) ss += __shfl_xor(ss, off, 64);
    __shared__ float red[4];
    if ((tid & 63) == 0) red[tid >> 6] = ss;
    __syncthreads();
    float inv = 1.0f / sqrtf((red[0] + red[1] + red[2] + red[3]) * (1.0f / DIM) + 1e-5f);
    const float4* gr = (const float4*)gamma;
    float4 g0 = gr[tid], g1 = gr[tid + 256];
    float v[8] = { a0.x*inv*g0.x, a0.y*inv*g0.y, a0.z*inv*g0.z, a0.w*inv*g0.w,
                   a1.x*inv*g1.x, a1.y*inv*g1.y, a1.z*inv*g1.z, a1.w*inv*g1.w };
    f16x4 h0, l0, h1, l1;
    #pragma unroll
    for (int i = 0; i < 4; i++) {
        f16 h = (f16)v[i];   h0[i] = h; l0[i] = (f16)(v[i]   - (float)h);
        f16 g = (f16)v[i+4]; h1[i] = g; l1[i] = (f16)(v[i+4] - (float)g);
    }
    size_t base = (size_t)row * DIM + tid * 4;
    *(f16x4*)&oh[base] = h0;  *(f16x4*)&oh[base + 1024] = h1;
    *(f16x4*)&ol[base] = l0;  *(f16x4*)&ol[base + 1024] = l1;
}

// ------------- fp32 -> transposed fp16 hi/lo (weights) -------------
template<bool WLO>
__global__ __launch_bounds__(256) void transpose_split_k(
    const float* __restrict__ in, f16* __restrict__ oh, f16* __restrict__ ol,
    int ldin, int outld)
{
    __shared__ float t[32][33];
    int tx = threadIdx.x, ty = threadIdx.y;
    int c0 = blockIdx.x * 32, r0 = blockIdx.y * 32;
    #pragma unroll
    for (int yy = 0; yy < 4; yy++)
        t[ty + yy*8][tx] = in[(size_t)(r0 + ty + yy*8) * ldin + c0 + tx];
    __syncthreads();
    #pragma unroll
    for (int yy = 0; yy < 4; yy++) {
        float v = t[tx][ty + yy*8];
        size_t o = (size_t)(c0 + ty + yy*8) * outld + r0 + tx;
        f16 h = (f16)v; oh[o] = h;
        if (WLO) ol[o] = (f16)(v - (float)h);
    }
}

// ------------- fp16 -> transposed fp16 (v slice) -------------
__global__ __launch_bounds__(256) void transpose_f16_k(
    const f16* __restrict__ in, f16* __restrict__ out, int ldin, int outld)
{
    __shared__ f16 t[32][33];
    int tx = threadIdx.x, ty = threadIdx.y;
    int c0 = blockIdx.x * 32, r0 = blockIdx.y * 32;
    #pragma unroll
    for (int yy = 0; yy < 4; yy++)
        t[ty + yy*8][tx] = in[(size_t)(r0 + ty + yy*8) * ldin + c0 + tx];
    __syncthreads();
    #pragma unroll
    for (int yy = 0; yy < 4; yy++)
        out[(size_t)(c0 + ty + yy*8) * outld + r0 + tx] = t[tx][ty + yy*8];
}

// --- tile-granular V suffix sums: Vsuft[t][d] = sum_{j >= 64t} V[j][d], t=0..32 ---
__global__ __launch_bounds__(64) void vsuft_k(
    const f16* __restrict__ Vt, float* __restrict__ Vsuft)
{
    int d = blockIdx.x, t = threadIdx.x;
    float s = 0.f;
    if (t < 32) {
        const f16* row = Vt + (size_t)d * SEQ + t * 64;
        #pragma unroll
        for (int u = 0; u < 64; u++) s += (float)row[u];
    }
    #pragma unroll
    for (int off = 1; off < 64; off <<= 1) {
        float v = __shfl_down(s, off, 64);
        s += (t + off < 64) ? v : 0.f;
    }
    if (t <= 32) Vsuft[t * DH + d] = (t < 32) ? s : 0.f;
}

__global__ void init_counter_k(int* c) { c[0] = 0; }

// ---------------- split-precision MFMA GEMM (m97-style staging) ----------------
template<int PASSES, int OUTMODE>
__global__ __launch_bounds__(256) void gemm_k(
    const f16* __restrict__ Ah, const f16* __restrict__ Al,
    const f16* __restrict__ Bh, const f16* __restrict__ Bl,
    float* __restrict__ C, f16* __restrict__ Ch, f16* __restrict__ Cl,
    int N, int K, float scale, int scale_cols)
{
    __shared__ f16 sa_h[128 * 32];
    __shared__ f16 sb_h[128 * 32];
    __shared__ f16 sa_l[PASSES == 3 ? 128 * 32 : 8];
    __shared__ f16 sb_l[PASSES == 3 ? 128 * 32 : 8];
    int tid = threadIdx.x;
    int wave = tid >> 6, lane = tid & 63, quad = lane >> 4, l16 = lane & 15;
    int m0 = blockIdx.x * 128, n0 = blockIdx.y * 128;
    int wm = (wave & 1) * 64, wn = (wave >> 1) * 64;
    f32x4 acc[4][4] = {};

    int r0s = wave * 16 + (lane >> 2);
    int cs  = (lane & 3) * 8;
    const f16* gA0 = Ah + (size_t)(m0 + r0s) * K + cs;
    const f16* gA1 = Ah + (size_t)(m0 + r0s + 64) * K + cs;
    const f16* gB0 = Bh + (size_t)(n0 + r0s) * K + cs;
    const f16* gB1 = Bh + (size_t)(n0 + r0s + 64) * K + cs;
    const f16* hA0 = Al + (size_t)(m0 + r0s) * K + cs;
    const f16* hA1 = Al + (size_t)(m0 + r0s + 64) * K + cs;
    const f16* hB0 = Bl + (size_t)(n0 + r0s) * K + cs;
    const f16* hB1 = Bl + (size_t)(n0 + r0s + 64) * K + cs;
    f16* lA0 = &sa_h[(size_t)r0s * 32 + cs];
    f16* lA1 = &sa_h[(size_t)(r0s + 64) * 32 + cs];
    f16* lB0 = &sb_h[(size_t)r0s * 32 + cs];
    f16* lB1 = &sb_h[(size_t)(r0s + 64) * 32 + cs];
    f16* mA0 = &sa_l[(size_t)r0s * 32 + cs];
    f16* mA1 = &sa_l[(size_t)(r0s + 64) * 32 + cs];
    f16* mB0 = &sb_l[(size_t)r0s * 32 + cs];
    f16* mB1 = &sb_l[(size_t)(r0s + 64) * 32 + cs];

    for (int k0 = 0; k0 < K; k0 += 32) {
        __syncthreads();
        gload16(gA0 + k0, lA0);
        gload16(gA1 + k0, lA1);
        gload16(gB0 + k0, lB0);
        gload16(gB1 + k0, lB1);
        if constexpr (PASSES == 3) {
            gload16(hA0 + k0, mA0);
            gload16(hA1 + k0, mA1);
            gload16(hB0 + k0, mB0);
            gload16(hB1 + k0, mB1);
        }
        __syncthreads();
        f16x8 ah[4], bh[4], al[4], bl[4];
        #pragma unroll
        for (int t = 0; t < 4; t++) {
            ah[t] = *(const f16x8*)&sa_h[(wm + t*16 + l16) * 32 + quad * 8];
            bh[t] = *(const f16x8*)&sb_h[(wn + t*16 + l16) * 32 + quad * 8];
        }
        if constexpr (PASSES == 3) {
            #pragma unroll
            for (int t = 0; t < 4; t++) {
                al[t] = *(const f16x8*)&sa_l[(wm + t*16 + l16) * 32 + quad * 8];
                bl[t] = *(const f16x8*)&sb_l[(wn + t*16 + l16) * 32 + quad * 8];
            }
        }
        #pragma unroll
        for (int i = 0; i < 4; i++)
            #pragma unroll
            for (int j = 0; j < 4; j++) {
                acc[i][j] = __builtin_amdgcn_mfma_f32_16x16x32_f16(ah[i], bh[j], acc[i][j], 0, 0, 0);
                if constexpr (PASSES == 3) {
                    acc[i][j] = __builtin_amdgcn_mfma_f32_16x16x32_f16(ah[i], bl[j], acc[i][j], 0, 0, 0);
                    acc[i][j] = __builtin_amdgcn_mfma_f32_16x16x32_f16(al[i], bh[j], acc[i][j], 0, 0, 0);
                }
            }
    }
    #pragma unroll
    for (int i = 0; i < 4; i++)
        #pragma unroll
        for (int j = 0; j < 4; j++) {
            int row = m0 + wm + i*16 + quad*4;
            int col = n0 + wn + j*16 + l16;
            float s = (col < scale_cols) ? scale : 1.0f;
            #pragma unroll
            for (int r = 0; r < 4; r++) {
                float v = acc[i][j][r] * s;
                if constexpr (OUTMODE == 0) {
                    C[(size_t)(row + r) * N + col] = v;
                } else {
                    f16 h = (f16)v;
                    Ch[(size_t)(row + r) * N + col] = h;
                    Cl[(size_t)(row + r) * N + col] = (f16)(v - (float)h);
                }
            }
        }
}

// ---------------- barrier-free per-wave flash attention ----------------
// Transposed MFMA roles: s^T = K·Q^T (A=K rows j, B=Q rows i); o^T = V^T·P^T.
// Each wave owns 16 q-rows x one j-chunk; K/V frags from global (L2-resident);
// bias DMA'd into double-buffered swizzled LDS slice. No __syncthreads.
__global__ __launch_bounds__(256) void attn2_k(
    const f16* __restrict__ Ph, const f16* __restrict__ Pl,
    const f16* __restrict__ Vt, const float* __restrict__ bias,
    const float* __restrict__ Vsuft, f16* __restrict__ Out,
    char* __restrict__ partial, int* __restrict__ counter)
{
    __shared__ float sbias[4 * 2 * 1024];   // [wave][buf][16 rows][16 chunks of 4 f32], swizzled
    __shared__ f16 sp[4 * 16 * 72];         // per-wave P round-trip
    int tid = threadIdx.x, wave = tid >> 6, lane = tid & 63;
    int quad = lane >> 4, l16 = lane & 15;
    float* mybias = &sbias[wave * 2048];
    f16* mysp = &sp[wave * 1152];
    // DMA lane map (row within 16, swizzled source chunk)
    int dma_r = lane >> 4;          // +qq*4
    int dma_c = lane & 15;
    f32x4 zero = {0.f, 0.f, 0.f, 0.f};

    for (;;) {
        int u0;
        if (lane == 0) u0 = atomicAdd(counter, 1);
        int u = __shfl(u0, 0, 64);
        if (u >= NUNITS2) break;

        int h = u & 15, t = u >> 4;
        int g, chunk, n;
        if (t < 128)      { g = 127 - (t >> 2); chunk = t & 3; n = 4; }
        else if (t < 224) { int s5 = t - 128; int q5 = s5 / 3; g = 95 - q5; chunk = s5 - q5 * 3; n = 3; }
        else if (t < 288) { int s5 = t - 224; g = 63 - (s5 >> 1); chunk = s5 & 1; n = 2; }
        else              { g = 31 - (t - 288); chunk = 0; n = 1; }
        int c = (g >> 2) + 1;
        int bse = c / n, rem = c % n;
        int jt0 = chunk * bse + (chunk < rem ? chunk : rem);
        int jt1 = jt0 + bse + (chunk < rem ? 1 : 0);
        int ig = g * 16 + l16;
        const float* bgh = bias + (size_t)h * SEQ * SEQ + (size_t)(g * 16) * SEQ;

        // Q fragments (B operand: n = i = l16, k = d)
        f16x8 qh[4], ql[4];
        #pragma unroll
        for (int kt = 0; kt < 4; kt++) {
            size_t off = (size_t)ig * NKV + h * DH + kt * 32 + quad * 8;
            qh[kt] = *(const f16x8*)(Ph + off);
            ql[kt] = *(const f16x8*)(Pl + off);
        }
        f32x4 o[8];
        #pragma unroll
        for (int dt = 0; dt < 8; dt++) o[dt] = zero;
        float mrun = -1e30f, lrun = 0.f;

        // stage first bias tile into buf 0
        {
            int j0 = jt0 * 64;
            #pragma unroll
            for (int qq = 0; qq < 4; qq++) {
                int rl = qq * 4 + dma_r;
                const float* src = bgh + (size_t)rl * SEQ + j0 + ((dma_c ^ rl) << 2);
                gload16f(src, mybias + qq * 256);
            }
        }

        int bi = 0;
        for (int jt = jt0; jt < jt1; jt++, bi ^= 1) {
            int j0 = jt * 64;
            // ---- QK: A = K rows (global, L2-resident), B = Q (regs) ----
            f32x4 s[4];
            #pragma unroll
            for (int nt = 0; nt < 4; nt++) {
                const f16* kb = Ph + (size_t)(j0 + nt * 16 + l16) * NKV + KOFF + quad * 8;
                const f16* lb = Pl + (size_t)(j0 + nt * 16 + l16) * NKV + KOFF + quad * 8;
                f16x8 kh[4], kl[4];
                #pragma unroll
                for (int kt = 0; kt < 4; kt++) {
                    kh[kt] = *(const f16x8*)(kb + kt * 32);
                    kl[kt] = *(const f16x8*)(lb + kt * 32);
                }
                s[nt] = zero;
                #pragma unroll
                for (int kt = 0; kt < 4; kt++) {
                    s[nt] = __builtin_amdgcn_mfma_f32_16x16x32_f16(kh[kt], qh[kt], s[nt], 0, 0, 0);
                    s[nt] = __builtin_amdgcn_mfma_f32_16x16x32_f16(kl[kt], qh[kt], s[nt], 0, 0, 0);
                    s[nt] = __builtin_amdgcn_mfma_f32_16x16x32_f16(kh[kt], ql[kt], s[nt], 0, 0, 0);
                }
            }
            // ---- bias (LDS, swizzled, f32x4 per nt) + faithful mask ----
            __builtin_amdgcn_s_waitcnt(0x0F70);  // vmcnt(0): bias DMA for this tile drained
            const float* bb = mybias + bi * 1024;
            #pragma unroll
            for (int nt = 0; nt < 4; nt++) {
                f32x4 bv = *(const f32x4*)&bb[(l16 << 6) + (((nt * 4 + quad) ^ l16) << 2)];
                #pragma unroll
                for (int r = 0; r < 4; r++) {
                    int jg = j0 + nt * 16 + quad * 4 + r;
                    s[nt][r] = (jg <= ig) ? (s[nt][r] + bv[r]) : 1e-10f;
                }
            }
            // ---- online softmax (per-lane state for row i = l16) ----
            float mx = -1e30f;
            #pragma unroll
            for (int nt = 0; nt < 4; nt++)
                #pragma unroll
                for (int r = 0; r < 4; r++) mx = fmaxf(mx, s[nt][r]);
            mx = fmaxf(mx, __shfl_xor(mx, 16, 64));
            mx = fmaxf(mx, __shfl_xor(mx, 32, 64));
            float mn = fmaxf(mrun, mx);
            float alpha = __expf(mrun - mn);
            mrun = mn;
            float rs = 0.f;
            #pragma unroll
            for (int nt = 0; nt < 4; nt++) {
                f16x4 pv;
                #pragma unroll
                for (int r = 0; r < 4; r++) {
                    float p = __expf(s[nt][r] - mn);
                    rs += p; pv[r] = (f16)p;
                }
                *(f16x4*)&mysp[l16 * 72 + nt * 16 + quad * 4] = pv;
            }
            rs += __shfl_xor(rs, 16, 64);
            rs += __shfl_xor(rs, 32, 64);
            lrun = lrun * alpha + rs;
            #pragma unroll
            for (int dt = 0; dt < 8; dt++) o[dt] *= alpha;
            // ---- PV: A = V^T rows d (global), B = P (LDS) ----
            #pragma unroll
            for (int ks = 0; ks < 2; ks++) {
                f16x8 pa = *(const f16x8*)&mysp[l16 * 72 + ks * 32 + quad * 8];
                #pragma unroll
                for (int dt = 0; dt < 8; dt++) {
                    f16x8 va = *(const f16x8*)(Vt + (size_t)(dt * 16 + l16) * SEQ + j0 + ks * 32 + quad * 8);
                    o[dt] = __builtin_amdgcn_mfma_f32_16x16x32_f16(va, pa, o[dt], 0, 0, 0);
                }
            }
            // ---- prefetch next tile's bias (in flight across next QK phase) ----
            if (jt + 1 < jt1) {
                int j0n = (jt + 1) * 64;
                #pragma unroll
                for (int qq = 0; qq < 4; qq++) {
                    int rl = qq * 4 + dma_r;
                    const float* src = bgh + (size_t)rl * SEQ + j0n + ((dma_c ^ rl) << 2);
                    gload16f(src, mybias + (bi ^ 1) * 1024 + qq * 256);
                }
            }
        }

        if (n == 1) {
            // direct epilogue with exact analytic masked tail (j >= 64c)
            int nm = SEQ - 64 * c;
            float mf = fmaxf(mrun, 1e-10f);
            float al = __expf(mrun - mf);
            float pm = (nm > 0) ? __expf(1e-10f - mf) : 0.f;
            float lf = lrun * al + (float)nm * pm;
            float inv = 1.0f / lf;
            #pragma unroll
            for (int dt = 0; dt < 8; dt++) {
                f32x4 vs = *(const f32x4*)&Vsuft[c * DH + dt * 16 + quad * 4];
                f16x4 ov;
                #pragma unroll
                for (int r = 0; r < 4; r++)
                    ov[r] = (f16)((o[dt][r] * al + pm * vs[r]) * inv);
                *(f16x4*)&Out[(size_t)ig * DIM + h * DH + dt * 16 + quad * 4] = ov;
            }
        } else {
            // partial record (normalized o, m, l)
            int cg = (g < 64) ? (g - 32) * 2 : (g < 96) ? 64 + (g - 64) * 3 : 160 + (g - 96) * 4;
            char* rec = partial + ((size_t)h * RECPH + cg + chunk) * RECB;
            f16* on = (f16*)rec;
            float inv = 1.0f / lrun;
            #pragma unroll
            for (int dt = 0; dt < 8; dt++) {
                f16x4 ov;
                #pragma unroll
                for (int r = 0; r < 4; r++) ov[r] = (f16)(o[dt][r] * inv);
                *(f16x4*)&on[l16 * DH + dt * 16 + quad * 4] = ov;
            }
            if (quad == 0) {
                *(float*)(rec + 4096 + l16 * 4) = mrun;
                *(float*)(rec + 4160 + l16 * 4) = lrun;
            }
        }
    }
}

// ---------------- merge j-chunks for g >= 32 ----------------
__global__ __launch_bounds__(64) void attn_merge2_k(
    const char* __restrict__ partial, const float* __restrict__ Vsuft,
    f16* __restrict__ Out)
{
    int b = blockIdx.x;             // 96*16 = 1536
    int g = 32 + (b >> 4), h = b & 15;
    int n = (g >> 5) + 1;           // 2..4 chunks
    int c = (g >> 2) + 1;
    int t = threadIdx.x;
    int row = t >> 2, cq = t & 3;   // 16 rows x 4 col-chunks of 32
    int cg = (g < 64) ? (g - 32) * 2 : (g < 96) ? 64 + (g - 64) * 3 : 160 + (g - 96) * 4;
    const char* rec0 = partial + ((size_t)h * RECPH + cg) * RECB;

    float mk[4], lk[4], w[4];
    float ms = -1e30f;
    for (int k = 0; k < n; k++) {
        const char* r = rec0 + (size_t)k * RECB;
        mk[k] = *(const float*)(r + 4096 + row * 4);
        lk[k] = *(const float*)(r + 4160 + row * 4);
        ms = fmaxf(ms, mk[k]);
    }
    float L = 0.f;
    for (int k = 0; k < n; k++) { w[k] = __expf(mk[k] - ms) * lk[k]; L += w[k]; }

    float acc[32];
    #pragma unroll
    for (int e = 0; e < 32; e++) acc[e] = 0.f;
    for (int k = 0; k < n; k++) {
        const f16* ov = (const f16*)(rec0 + (size_t)k * RECB) + row * DH + cq * 32;
        #pragma unroll
        for (int e = 0; e < 4; e++) {
            f16x8 v = *(const f16x8*)(ov + e * 8);
            #pragma unroll
            for (int uu = 0; uu < 8; uu++) acc[e * 8 + uu] += w[k] * (float)v[uu];
        }
    }
    int ig = g * 16 + row;
    int nm = SEQ - 64 * c;
    float mf = fmaxf(ms, 1e-10f);
    float al = __expf(ms - mf);
    float pm = (nm > 0) ? __expf(1e-10f - mf) : 0.f;
    float lf = L * al + (float)nm * pm;
    float inv = 1.0f / lf;
    const float* vs = Vsuft + c * DH + cq * 32;
    f16* op = Out + (size_t)ig * DIM + h * DH + cq * 32;
    #pragma unroll
    for (int e = 0; e < 4; e++) {
        f16x8 ov;
        #pragma unroll
        for (int uu = 0; uu < 8; uu++)
            ov[uu] = (f16)((acc[e * 8 + uu] * al + pm * vs[e * 8 + uu]) * inv);
        *(f16x8*)(op + e * 8) = ov;
    }
}

// ---------------- host orchestration ----------------
extern "C" void kernel_launch(void* const* d_in, const int* in_sizes, int n_in,
                              void* d_out, int out_size, void* d_ws, size_t ws_size,
                              hipStream_t stream)
{
    const float* x     = (const float*)d_in[0];
    const float* bias  = (const float*)d_in[1];
    const float* gamma = (const float*)d_in[2];
    const float* wq    = (const float*)d_in[3];
    const float* wk    = (const float*)d_in[4];
    const float* wv    = (const float*)d_in[5];
    const float* wo    = (const float*)d_in[6];
    float* out = (float*)d_out;
    char* ws = (char*)d_ws;

    const size_t MB = 1024 * 1024;
    f16* xn_h   = (f16*)(ws);                    // [0,8)   xn hi -> attn_o
    f16* xn_l   = (f16*)(ws + 8  * MB);          // [8,16)  xn lo -> vT/vsuft/counter
    f16* wT_h   = (f16*)(ws + 16 * MB);          // [16,25) -> partials after proj
    f16* wT_l   = (f16*)(ws + 25 * MB);          // [25,34)
    char* partial = ws + 16 * MB;                // 19.5 MB over dead wT
    f16* woT_h  = (f16*)(ws + 36 * MB);          // [36,44)
    f16* proj_h = (f16*)(ws + 44 * MB);          // [44,53)
    f16* proj_l = (f16*)(ws + 53 * MB);          // [53,62)
    f16* attn_o = xn_h;
    f16* vT     = (f16*)(ws + 8 * MB);           // [8, 8.5) post-proj
    float* vsuft = (float*)(ws + 8 * MB + 512 * 1024);   // 16.9 KB
    int* counter = (int*)(ws + 9 * MB);

    dim3 tb(32, 8);

    rmsnorm_split_k<<<SEQ, 256, 0, stream>>>(x, gamma, xn_h, xn_l);

    transpose_split_k<true><<<dim3(64, 64), tb, 0, stream>>>(wq, wT_h, wT_l, DIM, DIM);
    transpose_split_k<true><<<dim3(4, 64),  tb, 0, stream>>>(wk, wT_h + (size_t)KOFF * DIM,
                                                             wT_l + (size_t)KOFF * DIM, DH, DIM);
    transpose_split_k<true><<<dim3(4, 64),  tb, 0, stream>>>(wv, wT_h + (size_t)VOFF * DIM,
                                                             wT_l + (size_t)VOFF * DIM, DH, DIM);
    transpose_split_k<false><<<dim3(64, 64), tb, 0, stream>>>(wo, woT_h, nullptr, DIM, DIM);

    gemm_k<3, 1><<<dim3(16, 18), 256, 0, stream>>>(xn_h, xn_l, wT_h, wT_l,
                                                   nullptr, proj_h, proj_l,
                                                   NKV, DIM, QK_SCALE, DIM);

    transpose_f16_k<<<dim3(4, 64), tb, 0, stream>>>(proj_h + VOFF, vT, NKV, SEQ);
    vsuft_k<<<DH, 64, 0, stream>>>(vT, vsuft);
    init_counter_k<<<1, 1, 0, stream>>>(counter);

    attn2_k<<<768, 256, 0, stream>>>(proj_h, proj_l, vT, bias, vsuft, attn_o,
                                     partial, counter);
    attn_merge2_k<<<1536, 64, 0, stream>>>(partial, vsuft, attn_o);

    gemm_k<1, 0><<<dim3(16, 16), 256, 0, stream>>>(attn_o, attn_o, woT_h, woT_h,
                                                   out, nullptr, nullptr,
                                                   DIM, DIM, 1.0f, 0);
}